// Round 9
// baseline (360.479 us; speedup 1.0000x reference)
//
#include <hip/hip_runtime.h>

#define DIM 64
#define DEA 32

__device__ __forceinline__ unsigned short f2bf(float f) {
    const unsigned u = __float_as_uint(f);
    return (unsigned short)((u + 0x7FFFu + ((u >> 16) & 1u)) >> 16);   // RNE
}
__device__ __forceinline__ float bflo(unsigned u) { return __uint_as_float(u << 16); }
__device__ __forceinline__ float bfhi(unsigned u) { return __uint_as_float(u & 0xFFFF0000u); }

// ---------------------------------------------------------------------------
// One-time: combined score weight  M = (Wq @ We^T)*0.125  [64][32],
// bqe = (bq @ We^T)*0.125.  (score scale folded in; exact pow2)
// ---------------------------------------------------------------------------
__global__ __launch_bounds__(256) void wqe_prep_kernel(
    const float* __restrict__ wq1, const float* __restrict__ bq1, const float* __restrict__ we1,
    const float* __restrict__ wq2, const float* __restrict__ bq2, const float* __restrict__ we2,
    float* __restrict__ w1out, float* __restrict__ b1out,
    float* __restrict__ w2out, float* __restrict__ b2out)
{
    const float* wq = blockIdx.x ? wq2 : wq1;
    const float* bq = blockIdx.x ? bq2 : bq1;
    const float* we = blockIdx.x ? we2 : we1;
    float* wout = blockIdx.x ? w2out : w1out;
    float* bout = blockIdx.x ? b2out : b1out;

    __shared__ float lq[64 * 64];
    __shared__ float lweT[64 * 33];
    const int tid = threadIdx.x;
    {
        const float4* s4 = (const float4*)wq;
        float4* d4 = (float4*)lq;
        #pragma unroll
        for (int i = 0; i < 4; ++i) d4[tid + i * 256] = s4[tid + i * 256];
        const float4* e4 = (const float4*)we;
        #pragma unroll
        for (int t = 0; t < 2; ++t) {
            const int f = tid + t * 256;
            const int j = f >> 4;
            const int o4 = (f & 15) * 4;
            const float4 v = e4[f];
            lweT[(o4 + 0) * 33 + j] = v.x;
            lweT[(o4 + 1) * 33 + j] = v.y;
            lweT[(o4 + 2) * 33 + j] = v.z;
            lweT[(o4 + 3) * 33 + j] = v.w;
        }
    }
    __syncthreads();
    const int j = tid & 31;
    const int c0 = (tid >> 5) * 8;
    for (int c = c0; c < c0 + 8; ++c) {
        float acc = 0.f;
        #pragma unroll 8
        for (int o = 0; o < 64; ++o) acc = fmaf(lq[c * 64 + o], lweT[o * 33 + j], acc);
        wout[c * 32 + j] = acc * 0.125f;
    }
    if (tid < 32) {
        float acc = 0.f;
        #pragma unroll 8
        for (int o = 0; o < 64; ++o) acc = fmaf(bq[o], lweT[o * 33 + tid], acc);
        bout[tid] = acc * 0.125f;
    }
}

// ---------------------------------------------------------------------------
// Node linear v3: 32 nodes/block; q scaled by 0.125; k,v as bf16.
// ---------------------------------------------------------------------------
__global__ __launch_bounds__(256) void node_lin_kernel(
    const float* __restrict__ x,
    const float* __restrict__ wq, const float* __restrict__ bq,
    const float* __restrict__ wk, const float* __restrict__ bk,
    const float* __restrict__ wv, const float* __restrict__ bv,
    const float* __restrict__ wsk, const float* __restrict__ bsk,
    const float* __restrict__ wqe_w, const float* __restrict__ bqe,
    float* __restrict__ q, unsigned short* __restrict__ kvb,
    float* __restrict__ agg, float* __restrict__ qwe, int n_nodes)
{
    __shared__ float lw[16 * 256];
    __shared__ float lxT[64 * 36];
    __shared__ float lwqe[64 * 32];
    const int tid = threadIdx.x;
    const int base = blockIdx.x * 32;

    {
        #pragma unroll
        for (int t = 0; t < 2; ++t) {
            const int f = tid + t * 256;
            const int node = f >> 4;
            const int c4 = (f & 15) * 4;
            const int n = base + node;
            float4 val = make_float4(0.f, 0.f, 0.f, 0.f);
            if (n < n_nodes) val = *(const float4*)&x[(size_t)n * DIM + c4];
            lxT[(c4 + 0) * 36 + node] = val.x;
            lxT[(c4 + 1) * 36 + node] = val.y;
            lxT[(c4 + 2) * 36 + node] = val.z;
            lxT[(c4 + 3) * 36 + node] = val.w;
        }
        const float4* s4 = (const float4*)wqe_w;
        float4* d4 = (float4*)lwqe;
        d4[tid] = s4[tid];
        d4[tid + 256] = s4[tid + 256];
    }

    const int m = tid >> 6;
    const int oc = tid & 63;
    const float* wsrc = (m == 0) ? wq : (m == 1) ? wk : (m == 2) ? wv : wsk;
    const float bias = ((m == 0) ? bq : (m == 1) ? bk : (m == 2) ? bv : bsk)[oc];

    float acc[32];
    #pragma unroll
    for (int r = 0; r < 32; ++r) acc[r] = 0.f;

    for (int kc = 0; kc < 4; ++kc) {
        __syncthreads();
        #pragma unroll
        for (int i = 0; i < 4; ++i) {
            const int f = oc + i * 64;
            const int kk = f >> 4;
            const int c4 = (f & 15) * 4;
            const float4 w4 = *(const float4*)&wsrc[(size_t)(kc * 16 + kk) * DIM + c4];
            *(float4*)&lw[kk * 256 + m * 64 + c4] = w4;
        }
        __syncthreads();
        #pragma unroll
        for (int kk = 0; kk < 16; ++kk) {
            const float wv_ = lw[kk * 256 + tid];
            const float* xrow = &lxT[(kc * 16 + kk) * 36];
            #pragma unroll
            for (int r4 = 0; r4 < 8; ++r4) {
                const float4 xv = *(const float4*)&xrow[r4 * 4];
                acc[r4 * 4 + 0] = fmaf(xv.x, wv_, acc[r4 * 4 + 0]);
                acc[r4 * 4 + 1] = fmaf(xv.y, wv_, acc[r4 * 4 + 1]);
                acc[r4 * 4 + 2] = fmaf(xv.z, wv_, acc[r4 * 4 + 2]);
                acc[r4 * 4 + 3] = fmaf(xv.w, wv_, acc[r4 * 4 + 3]);
            }
        }
    }

    #pragma unroll
    for (int r = 0; r < 32; ++r) {
        const int n = base + r;
        if (n < n_nodes) {
            const float val = acc[r] + bias;
            if (m == 0)      q[(size_t)n * DIM + oc]            = val * 0.125f;
            else if (m == 1) kvb[(size_t)n * 128 + oc]          = f2bf(val);
            else if (m == 2) kvb[(size_t)n * 128 + 64 + oc]     = f2bf(val);
            else             agg[(size_t)n * DIM + oc]          = val;   // root skip
        }
    }

    // qwe phase (weights pre-scaled by 0.125)
    {
        const int j = tid & 31;
        const int r0 = (tid >> 5) * 4;
        float a0 = 0.f, a1 = 0.f, a2 = 0.f, a3 = 0.f;
        #pragma unroll 8
        for (int c = 0; c < DIM; ++c) {
            const float wv_ = lwqe[c * 32 + j];
            const float4 xv = *(const float4*)&lxT[c * 36 + r0];
            a0 = fmaf(xv.x, wv_, a0);
            a1 = fmaf(xv.y, wv_, a1);
            a2 = fmaf(xv.z, wv_, a2);
            a3 = fmaf(xv.w, wv_, a3);
        }
        const float bb = bqe[j];
        const float av[4] = {a0 + bb, a1 + bb, a2 + bb, a3 + bb};
        #pragma unroll
        for (int i = 0; i < 4; ++i) {
            const int n = base + r0 + i;
            if (n < n_nodes) qwe[(size_t)n * DEA + j] = av[i];
        }
    }
}

// ---------------------------------------------------------------------------
// CSR build over dst: histogram -> 3-pass multi-block scan -> scatter
// ---------------------------------------------------------------------------
__global__ __launch_bounds__(256) void hist_kernel(
    const int* __restrict__ dst, int* __restrict__ counts, int n_edges, int n_nodes)
{
    const int eid = blockIdx.x * 256 + threadIdx.x;
    if (eid >= n_edges) return;
    int d = dst[eid];
    d = (d < 0) ? 0 : ((d >= n_nodes) ? n_nodes - 1 : d);
    atomicAdd(&counts[d], 1);
}

__global__ __launch_bounds__(256) void scan_pass1_kernel(
    const int* __restrict__ counts, int* __restrict__ row_ptr,
    int* __restrict__ blksum, int n)
{
    const int tid = threadIdx.x;
    const int lane = tid & 63;
    const int base = blockIdx.x * 1024 + tid * 4;
    int c0 = 0, c1 = 0, c2 = 0, c3 = 0;
    if (base + 3 < n) {
        const int4 v = *(const int4*)&counts[base];
        c0 = v.x; c1 = v.y; c2 = v.z; c3 = v.w;
    } else {
        if (base + 0 < n) c0 = counts[base + 0];
        if (base + 1 < n) c1 = counts[base + 1];
        if (base + 2 < n) c2 = counts[base + 2];
        if (base + 3 < n) c3 = counts[base + 3];
    }
    const int tsum = c0 + c1 + c2 + c3;
    int incl = tsum;
    #pragma unroll
    for (int off = 1; off < 64; off <<= 1) {
        const int t = __shfl_up(incl, off, 64);
        if (lane >= off) incl += t;
    }
    __shared__ int wsum[4];
    const int wv = tid >> 6;
    if (lane == 63) wsum[wv] = incl;
    __syncthreads();
    int woff = 0;
    #pragma unroll
    for (int i = 0; i < 4; ++i) if (i < wv) woff += wsum[i];
    const int excl = woff + incl - tsum;
    if (base + 3 < n) {
        int4 o;
        o.x = excl; o.y = excl + c0; o.z = excl + c0 + c1; o.w = excl + c0 + c1 + c2;
        *(int4*)&row_ptr[base] = o;
    } else {
        if (base + 0 < n) row_ptr[base + 0] = excl;
        if (base + 1 < n) row_ptr[base + 1] = excl + c0;
        if (base + 2 < n) row_ptr[base + 2] = excl + c0 + c1;
        if (base + 3 < n) row_ptr[base + 3] = excl + c0 + c1 + c2;
    }
    if (tid == 255) blksum[blockIdx.x] = woff + incl;
}

__global__ __launch_bounds__(64) void scan_pass2_kernel(
    const int* __restrict__ blksum, int* __restrict__ blkoff,
    int* __restrict__ row_ptr, int nb, int n)
{
    const int lane = threadIdx.x;
    int carry = 0;
    for (int base = 0; base < nb; base += 64) {
        const int idx = base + lane;
        const int v = (idx < nb) ? blksum[idx] : 0;
        int incl = v;
        #pragma unroll
        for (int off = 1; off < 64; off <<= 1) {
            const int t = __shfl_up(incl, off, 64);
            if (lane >= off) incl += t;
        }
        if (idx < nb) blkoff[idx] = carry + incl - v;
        carry += __shfl(incl, 63, 64);
    }
    if (lane == 0) row_ptr[n] = carry;
}

__global__ __launch_bounds__(256) void scan_pass3_kernel(
    int* __restrict__ row_ptr, int* __restrict__ cursor,
    const int* __restrict__ blkoff, int n)
{
    const int base = blockIdx.x * 1024 + threadIdx.x * 4;
    const int off = blkoff[blockIdx.x];
    if (base + 3 < n) {
        int4 v = *(const int4*)&row_ptr[base];
        v.x += off; v.y += off; v.z += off; v.w += off;
        *(int4*)&row_ptr[base] = v;
        *(int4*)&cursor[base]  = v;
    } else {
        #pragma unroll
        for (int i = 0; i < 4; ++i) {
            if (base + i < n) {
                const int v = row_ptr[base + i] + off;
                row_ptr[base + i] = v;
                cursor[base + i]  = v;
            }
        }
    }
}

__global__ __launch_bounds__(256) void scatter_kernel(
    const int* __restrict__ dst, const int* __restrict__ src,
    int* __restrict__ cursor, int2* __restrict__ pair, int n_edges, int n_nodes)
{
    const int eid = blockIdx.x * 256 + threadIdx.x;
    if (eid >= n_edges) return;
    int d = dst[eid];
    d = (d < 0) ? 0 : ((d >= n_nodes) ? n_nodes - 1 : d);
    int s = src[eid];
    s = (s < 0) ? 0 : ((s >= n_nodes) ? n_nodes - 1 : s);
    const int pos = atomicAdd(&cursor[d], 1);
    pair[pos] = make_int2(eid, s);
}

// ---------------------------------------------------------------------------
// Fused aggregation v6: one wave per dst node; 8 edge-groups x 8 lanes.
// Software-pipelined: kv/ea double-buffered in regs; pair prefetched 2 ahead.
//   score = q.k[src] + qwe.ea ;  msg = sum p*v[src] ; sea = sum p*ea
//   out   = relu(skip + (msg + sea@We)/l)
// ---------------------------------------------------------------------------
__global__ __launch_bounds__(256) void fused_edge_kernel(
    const float* __restrict__ q, const float* __restrict__ qwe,
    const unsigned short* __restrict__ kvb, const float* __restrict__ ea,
    const float* __restrict__ we, const float* __restrict__ aggskip,
    const int* __restrict__ row_ptr, const int2* __restrict__ pair,
    float* __restrict__ h_out, int n_nodes)
{
    __shared__ float lw[DEA * DIM];   // 8 KB, We row-major [32][64]
    __shared__ float lsea[4][36];     // per-wave merged sea
    __shared__ float lmsg[4][72];     // per-wave merged msg
    const int tid = threadIdx.x;
    {
        const float4* s4 = (const float4*)we;
        float4* d4 = (float4*)lw;
        d4[tid] = s4[tid];
        d4[tid + 256] = s4[tid + 256];
    }
    __syncthreads();

    const int wave = tid >> 6;
    const int lane = tid & 63;
    const int g = lane >> 3;          // edge group 0..7
    const int j = lane & 7;           // channel slot: ch [j*8, j*8+8)
    const int node = blockIdx.x * 4 + wave;
    if (node >= n_nodes) return;

    const float4 qa  = *(const float4*)&q[(size_t)node * DIM + j * 8];
    const float4 qb  = *(const float4*)&q[(size_t)node * DIM + j * 8 + 4];
    const float4 qw4 = *(const float4*)&qwe[(size_t)node * DEA + j * 4];
    const int beg = row_ptr[node], end = row_ptr[node + 1];

    float m = -3.0e38f, l = 0.f;
    float4 msgA = make_float4(0.f, 0.f, 0.f, 0.f);
    float4 msgB = make_float4(0.f, 0.f, 0.f, 0.f);
    float4 sea  = make_float4(0.f, 0.f, 0.f, 0.f);

    if (beg < end) {
        const int last = end - 1;
        const int i00 = beg + g;
        // pair for step0 and step1 (clamped to valid indices)
        int2 prB = (i00 + 8 < end) ? pair[i00 + 8] : pair[(i00 < end) ? i00 : last];
        {
            // note: reload i00's pair for step-0 data (two independent loads)
        }
        const int2 pr0 = pair[(i00 < end) ? i00 : last];
        const unsigned short* kp0 = &kvb[(size_t)pr0.y * 128];
        uint4 kr0 = *(const uint4*)&kp0[j * 8];
        uint4 vr0 = *(const uint4*)&kp0[64 + j * 8];
        float4 ea0 = *(const float4*)&ea[(size_t)pr0.x * DEA + j * 4];

        for (int i0 = beg; i0 < end; i0 += 8) {
            const bool act = (i0 + g) < end;
            const bool more = (i0 + 8) < end;      // wave-uniform
            uint4 kr1, vr1;
            float4 ea1;
            int2 prC = prB;
            if (more) {
                // prefetch pair 2 steps ahead
                const int i2 = i0 + 16 + g;
                prC = (i2 < end) ? pair[i2] : prB;
                // prefetch kv/ea 1 step ahead (prB resident since last iter)
                const unsigned short* kpn = &kvb[(size_t)prB.y * 128];
                kr1 = *(const uint4*)&kpn[j * 8];
                vr1 = *(const uint4*)&kpn[64 + j * 8];
                ea1 = *(const float4*)&ea[(size_t)prB.x * DEA + j * 4];
            }

            float t0 = fmaf(qa.x, bflo(kr0.x), qw4.x * ea0.x);
            t0 = fmaf(qa.y, bfhi(kr0.x), t0);
            t0 = fmaf(qa.z, bflo(kr0.y), t0);
            t0 = fmaf(qa.w, bfhi(kr0.y), t0);
            t0 = fmaf(qw4.z, ea0.z, t0);
            float t1 = fmaf(qb.x, bflo(kr0.z), qw4.y * ea0.y);
            t1 = fmaf(qb.y, bfhi(kr0.z), t1);
            t1 = fmaf(qb.z, bflo(kr0.w), t1);
            t1 = fmaf(qb.w, bfhi(kr0.w), t1);
            t1 = fmaf(qw4.w, ea0.w, t1);
            float t = t0 + t1;
            t += __shfl_xor(t, 1, 64);
            t += __shfl_xor(t, 2, 64);
            t += __shfl_xor(t, 4, 64);
            const float score = act ? t : -3.0e38f;

            const float mn = fmaxf(m, score);
            const float p  = act ? __expf(score - mn) : 0.f;
            const float sc = __expf(m - mn);
            l = l * sc + p;
            msgA.x = fmaf(p, bflo(vr0.x), msgA.x * sc);
            msgA.y = fmaf(p, bfhi(vr0.x), msgA.y * sc);
            msgA.z = fmaf(p, bflo(vr0.y), msgA.z * sc);
            msgA.w = fmaf(p, bfhi(vr0.y), msgA.w * sc);
            msgB.x = fmaf(p, bflo(vr0.z), msgB.x * sc);
            msgB.y = fmaf(p, bfhi(vr0.z), msgB.y * sc);
            msgB.z = fmaf(p, bflo(vr0.w), msgB.z * sc);
            msgB.w = fmaf(p, bfhi(vr0.w), msgB.w * sc);
            sea.x = fmaf(p, ea0.x, sea.x * sc);
            sea.y = fmaf(p, ea0.y, sea.y * sc);
            sea.z = fmaf(p, ea0.z, sea.z * sc);
            sea.w = fmaf(p, ea0.w, sea.w * sc);
            m = mn;

            if (more) {
                kr0 = kr1; vr0 = vr1; ea0 = ea1;
                prB = prC;
            }
        }
    }

    // merge the 8 groups over g bits (xor 8, 16, 32)
    #pragma unroll
    for (int off = 8; off <= 32; off <<= 1) {
        const float m2 = __shfl_xor(m, off, 64);
        const float l2 = __shfl_xor(l, off, 64);
        float4 a2, b2, s2;
        a2.x = __shfl_xor(msgA.x, off, 64); a2.y = __shfl_xor(msgA.y, off, 64);
        a2.z = __shfl_xor(msgA.z, off, 64); a2.w = __shfl_xor(msgA.w, off, 64);
        b2.x = __shfl_xor(msgB.x, off, 64); b2.y = __shfl_xor(msgB.y, off, 64);
        b2.z = __shfl_xor(msgB.z, off, 64); b2.w = __shfl_xor(msgB.w, off, 64);
        s2.x = __shfl_xor(sea.x, off, 64);  s2.y = __shfl_xor(sea.y, off, 64);
        s2.z = __shfl_xor(sea.z, off, 64);  s2.w = __shfl_xor(sea.w, off, 64);
        const float mn = fmaxf(m, m2);
        const float w1 = __expf(m - mn);
        const float w2 = __expf(m2 - mn);
        l = l * w1 + l2 * w2;
        msgA.x = msgA.x * w1 + a2.x * w2; msgA.y = msgA.y * w1 + a2.y * w2;
        msgA.z = msgA.z * w1 + a2.z * w2; msgA.w = msgA.w * w1 + a2.w * w2;
        msgB.x = msgB.x * w1 + b2.x * w2; msgB.y = msgB.y * w1 + b2.y * w2;
        msgB.z = msgB.z * w1 + b2.z * w2; msgB.w = msgB.w * w1 + b2.w * w2;
        sea.x = sea.x * w1 + s2.x * w2;   sea.y = sea.y * w1 + s2.y * w2;
        sea.z = sea.z * w1 + s2.z * w2;   sea.w = sea.w * w1 + s2.w * w2;
        m = mn;
    }

    // stage merged state in per-wave LDS (any one group; use g==0)
    if (g == 0) {
        *(float4*)&lsea[wave][j * 4]     = sea;
        *(float4*)&lmsg[wave][j * 8]     = msgA;
        *(float4*)&lmsg[wave][j * 8 + 4] = msgB;
    }
    const float inv = (l > 0.f) ? (1.f / l) : 0.f;

    // epilogue: lane handles output channel = lane
    float e = 0.f;
    #pragma unroll 8
    for (int j2 = 0; j2 < DEA; ++j2)
        e = fmaf(lsea[wave][j2], lw[j2 * DIM + lane], e);
    const float msgc = lmsg[wave][lane];
    const float sk = aggskip[(size_t)node * DIM + lane];
    h_out[(size_t)node * DIM + lane] = fmaxf(fmaf(msgc + e, inv, sk), 0.f);
}

// ---------------------------------------------------------------------------
// Final: out = relu(concat(h1,h2) @ skip_w + skip_b), K=128
// ---------------------------------------------------------------------------
__global__ __launch_bounds__(256) void final_kernel(
    const float* __restrict__ h1, const float* __restrict__ h2,
    const float* __restrict__ w, const float* __restrict__ b,
    float* __restrict__ out, int n_nodes)
{
    __shared__ float lw[128 * DIM];   // 32 KB
    __shared__ float lx[16][128];     // 8 KB
    const int tid = threadIdx.x;
    {
        const float4* s4 = (const float4*)w;
        float4* d4 = (float4*)lw;
        #pragma unroll
        for (int i = 0; i < 8; ++i) d4[tid + i * 256] = s4[tid + i * 256];
    }
    const int base = blockIdx.x * 16;
    {
        #pragma unroll
        for (int t = 0; t < 2; ++t) {
            const int f = tid + t * 256;
            const int r = f >> 5;
            const int cf = f & 31;
            const int n = base + r;
            float4 val = make_float4(0.f, 0.f, 0.f, 0.f);
            if (n < n_nodes) {
                if (cf < 16) val = *(const float4*)&h1[(size_t)n * DIM + cf * 4];
                else         val = *(const float4*)&h2[(size_t)n * DIM + (cf - 16) * 4];
            }
            *(float4*)&lx[r][cf * 4] = val;
        }
    }
    __syncthreads();

    const int oc = tid & 63;
    const int nl = tid >> 6;
    float acc[4] = {0, 0, 0, 0};
    #pragma unroll 8
    for (int kk = 0; kk < 128; ++kk) {
        const float wv = lw[kk * DIM + oc];
        #pragma unroll
        for (int r = 0; r < 4; ++r)
            acc[r] = fmaf(lx[nl * 4 + r][kk], wv, acc[r]);
    }
    const float bv = b[oc];
    #pragma unroll
    for (int r = 0; r < 4; ++r) {
        const int n = base + nl * 4 + r;
        if (n < n_nodes) out[(size_t)n * DIM + oc] = fmaxf(acc[r] + bv, 0.f);
    }
}

// ---------------------------------------------------------------------------
extern "C" void kernel_launch(void* const* d_in, const int* in_sizes, int n_in,
                              void* d_out, int out_size, void* d_ws, size_t ws_size,
                              hipStream_t stream)
{
    const float* x     = (const float*)d_in[0];
    const int*   ei    = (const int*)d_in[1];
    const float* eattr = (const float*)d_in[2];
    const float *q1w = (const float*)d_in[3],  *q1b = (const float*)d_in[4];
    const float *k1w = (const float*)d_in[5],  *k1b = (const float*)d_in[6];
    const float *v1w = (const float*)d_in[7],  *v1b = (const float*)d_in[8];
    const float *e1w = (const float*)d_in[9];
    const float *s1w = (const float*)d_in[10], *s1b = (const float*)d_in[11];
    const float *q2w = (const float*)d_in[12], *q2b = (const float*)d_in[13];
    const float *k2w = (const float*)d_in[14], *k2b = (const float*)d_in[15];
    const float *v2w = (const float*)d_in[16], *v2b = (const float*)d_in[17];
    const float *e2w = (const float*)d_in[18];
    const float *s2w = (const float*)d_in[19], *s2b = (const float*)d_in[20];
    const float *skw = (const float*)d_in[21], *skb = (const float*)d_in[22];

    const int N = in_sizes[0] / DIM;
    const int E = in_sizes[1] / 2;
    const int* src = ei;
    const int* dst = ei + E;

    float* ws = (float*)d_ws;
    const size_t nf = (size_t)N * DIM;
    float* q    = ws;                          // nf
    unsigned short* kvb = (unsigned short*)(q + nf);  // N*128 ushorts = nf floats
    float* agg  = q + 2 * nf;                  // nf
    float* h1   = agg + nf;                    // nf
    float* h2   = h1 + nf;                     // nf
    float* qwe  = h2 + nf;                     // 32*N
    int2* pair    = (int2*)(qwe + (size_t)DEA * N);    // E int2
    int* cursor   = (int*)(pair + E);                  // N
    int* row_ptr  = cursor + ((N + 3) & ~3);           // N+1
    const int nb  = (N + 1023) / 1024;
    int* blksum   = row_ptr + ((N + 4) & ~3);          // nb
    int* blkoff   = blksum + ((nb + 3) & ~3);          // nb
    float* wqeW1  = (float*)(blkoff + ((nb + 3) & ~3));// 2048
    float* bqe1   = wqeW1 + 64 * 32;                   // 32
    float* wqeW2  = bqe1 + 32;                         // 2048
    float* bqe2   = wqeW2 + 64 * 32;                   // 32

    const int nblk = (N + 31) / 32;
    const int eblk = (E + 255) / 256;
    const int fblk = (N + 3) / 4;
    const int finblk = (N + 15) / 16;

    // ---------------- CSR over dst + combined score weights ----------------
    hipMemsetAsync(cursor, 0, (size_t)N * sizeof(int), stream);
    hist_kernel<<<eblk, 256, 0, stream>>>(dst, cursor, E, N);
    scan_pass1_kernel<<<nb, 256, 0, stream>>>(cursor, row_ptr, blksum, N);
    scan_pass2_kernel<<<1, 64, 0, stream>>>(blksum, blkoff, row_ptr, nb, N);
    scan_pass3_kernel<<<nb, 256, 0, stream>>>(row_ptr, cursor, blkoff, N);
    scatter_kernel<<<eblk, 256, 0, stream>>>(dst, src, cursor, pair, E, N);
    wqe_prep_kernel<<<2, 256, 0, stream>>>(q1w, q1b, e1w, q2w, q2b, e2w,
                                           wqeW1, bqe1, wqeW2, bqe2);

    // ---------------- layer 1 ----------------
    node_lin_kernel<<<nblk, 256, 0, stream>>>(x, q1w, q1b, k1w, k1b, v1w, v1b,
                                              s1w, s1b, wqeW1, bqe1,
                                              q, kvb, agg, qwe, N);
    fused_edge_kernel<<<fblk, 256, 0, stream>>>(q, qwe, kvb, eattr, e1w, agg,
                                                row_ptr, pair, h1, N);

    // ---------------- layer 2 ----------------
    node_lin_kernel<<<nblk, 256, 0, stream>>>(h1, q2w, q2b, k2w, k2b, v2w, v2b,
                                              s2w, s2b, wqeW2, bqe2,
                                              q, kvb, agg, qwe, N);
    fused_edge_kernel<<<fblk, 256, 0, stream>>>(q, qwe, kvb, eattr, e2w, agg,
                                                row_ptr, pair, h2, N);

    // ---------------- final skip MLP ----------------
    final_kernel<<<finblk, 256, 0, stream>>>(h1, h2, skw, skb, (float*)d_out, N);
}

// Round 10
// 359.024 us; speedup vs baseline: 1.0041x; 1.0041x over previous
//
#include <hip/hip_runtime.h>

#define DIM 64
#define DEA 32

__device__ __forceinline__ unsigned short f2bf(float f) {
    const unsigned u = __float_as_uint(f);
    return (unsigned short)((u + 0x7FFFu + ((u >> 16) & 1u)) >> 16);   // RNE
}
__device__ __forceinline__ float bflo(unsigned u) { return __uint_as_float(u << 16); }
__device__ __forceinline__ float bfhi(unsigned u) { return __uint_as_float(u & 0xFFFF0000u); }

// ---------------------------------------------------------------------------
// One-time: combined score weight  M = (Wq @ We^T)*0.125  [64][32],
// bqe = (bq @ We^T)*0.125.  (score scale folded in; exact pow2)
// ---------------------------------------------------------------------------
__global__ __launch_bounds__(256) void wqe_prep_kernel(
    const float* __restrict__ wq1, const float* __restrict__ bq1, const float* __restrict__ we1,
    const float* __restrict__ wq2, const float* __restrict__ bq2, const float* __restrict__ we2,
    float* __restrict__ w1out, float* __restrict__ b1out,
    float* __restrict__ w2out, float* __restrict__ b2out)
{
    const float* wq = blockIdx.x ? wq2 : wq1;
    const float* bq = blockIdx.x ? bq2 : bq1;
    const float* we = blockIdx.x ? we2 : we1;
    float* wout = blockIdx.x ? w2out : w1out;
    float* bout = blockIdx.x ? b2out : b1out;

    __shared__ float lq[64 * 64];
    __shared__ float lweT[64 * 33];
    const int tid = threadIdx.x;
    {
        const float4* s4 = (const float4*)wq;
        float4* d4 = (float4*)lq;
        #pragma unroll
        for (int i = 0; i < 4; ++i) d4[tid + i * 256] = s4[tid + i * 256];
        const float4* e4 = (const float4*)we;
        #pragma unroll
        for (int t = 0; t < 2; ++t) {
            const int f = tid + t * 256;
            const int j = f >> 4;
            const int o4 = (f & 15) * 4;
            const float4 v = e4[f];
            lweT[(o4 + 0) * 33 + j] = v.x;
            lweT[(o4 + 1) * 33 + j] = v.y;
            lweT[(o4 + 2) * 33 + j] = v.z;
            lweT[(o4 + 3) * 33 + j] = v.w;
        }
    }
    __syncthreads();
    const int j = tid & 31;
    const int c0 = (tid >> 5) * 8;
    for (int c = c0; c < c0 + 8; ++c) {
        float acc = 0.f;
        #pragma unroll 8
        for (int o = 0; o < 64; ++o) acc = fmaf(lq[c * 64 + o], lweT[o * 33 + j], acc);
        wout[c * 32 + j] = acc * 0.125f;
    }
    if (tid < 32) {
        float acc = 0.f;
        #pragma unroll 8
        for (int o = 0; o < 64; ++o) acc = fmaf(bq[o], lweT[o * 33 + tid], acc);
        bout[tid] = acc * 0.125f;
    }
}

// ---------------------------------------------------------------------------
// Node linear v3: 32 nodes/block; q scaled by 0.125; k,v as bf16.
// ---------------------------------------------------------------------------
__global__ __launch_bounds__(256) void node_lin_kernel(
    const float* __restrict__ x,
    const float* __restrict__ wq, const float* __restrict__ bq,
    const float* __restrict__ wk, const float* __restrict__ bk,
    const float* __restrict__ wv, const float* __restrict__ bv,
    const float* __restrict__ wsk, const float* __restrict__ bsk,
    const float* __restrict__ wqe_w, const float* __restrict__ bqe,
    float* __restrict__ q, unsigned short* __restrict__ kvb,
    float* __restrict__ agg, float* __restrict__ qwe, int n_nodes)
{
    __shared__ float lw[16 * 256];
    __shared__ float lxT[64 * 36];
    __shared__ float lwqe[64 * 32];
    const int tid = threadIdx.x;
    const int base = blockIdx.x * 32;

    {
        #pragma unroll
        for (int t = 0; t < 2; ++t) {
            const int f = tid + t * 256;
            const int node = f >> 4;
            const int c4 = (f & 15) * 4;
            const int n = base + node;
            float4 val = make_float4(0.f, 0.f, 0.f, 0.f);
            if (n < n_nodes) val = *(const float4*)&x[(size_t)n * DIM + c4];
            lxT[(c4 + 0) * 36 + node] = val.x;
            lxT[(c4 + 1) * 36 + node] = val.y;
            lxT[(c4 + 2) * 36 + node] = val.z;
            lxT[(c4 + 3) * 36 + node] = val.w;
        }
        const float4* s4 = (const float4*)wqe_w;
        float4* d4 = (float4*)lwqe;
        d4[tid] = s4[tid];
        d4[tid + 256] = s4[tid + 256];
    }

    const int m = tid >> 6;
    const int oc = tid & 63;
    const float* wsrc = (m == 0) ? wq : (m == 1) ? wk : (m == 2) ? wv : wsk;
    const float bias = ((m == 0) ? bq : (m == 1) ? bk : (m == 2) ? bv : bsk)[oc];

    float acc[32];
    #pragma unroll
    for (int r = 0; r < 32; ++r) acc[r] = 0.f;

    for (int kc = 0; kc < 4; ++kc) {
        __syncthreads();
        #pragma unroll
        for (int i = 0; i < 4; ++i) {
            const int f = oc + i * 64;
            const int kk = f >> 4;
            const int c4 = (f & 15) * 4;
            const float4 w4 = *(const float4*)&wsrc[(size_t)(kc * 16 + kk) * DIM + c4];
            *(float4*)&lw[kk * 256 + m * 64 + c4] = w4;
        }
        __syncthreads();
        #pragma unroll
        for (int kk = 0; kk < 16; ++kk) {
            const float wv_ = lw[kk * 256 + tid];
            const float* xrow = &lxT[(kc * 16 + kk) * 36];
            #pragma unroll
            for (int r4 = 0; r4 < 8; ++r4) {
                const float4 xv = *(const float4*)&xrow[r4 * 4];
                acc[r4 * 4 + 0] = fmaf(xv.x, wv_, acc[r4 * 4 + 0]);
                acc[r4 * 4 + 1] = fmaf(xv.y, wv_, acc[r4 * 4 + 1]);
                acc[r4 * 4 + 2] = fmaf(xv.z, wv_, acc[r4 * 4 + 2]);
                acc[r4 * 4 + 3] = fmaf(xv.w, wv_, acc[r4 * 4 + 3]);
            }
        }
    }

    #pragma unroll
    for (int r = 0; r < 32; ++r) {
        const int n = base + r;
        if (n < n_nodes) {
            const float val = acc[r] + bias;
            if (m == 0)      q[(size_t)n * DIM + oc]            = val * 0.125f;
            else if (m == 1) kvb[(size_t)n * 128 + oc]          = f2bf(val);
            else if (m == 2) kvb[(size_t)n * 128 + 64 + oc]     = f2bf(val);
            else             agg[(size_t)n * DIM + oc]          = val;   // root skip
        }
    }

    // qwe phase (weights pre-scaled by 0.125)
    {
        const int j = tid & 31;
        const int r0 = (tid >> 5) * 4;
        float a0 = 0.f, a1 = 0.f, a2 = 0.f, a3 = 0.f;
        #pragma unroll 8
        for (int c = 0; c < DIM; ++c) {
            const float wv_ = lwqe[c * 32 + j];
            const float4 xv = *(const float4*)&lxT[c * 36 + r0];
            a0 = fmaf(xv.x, wv_, a0);
            a1 = fmaf(xv.y, wv_, a1);
            a2 = fmaf(xv.z, wv_, a2);
            a3 = fmaf(xv.w, wv_, a3);
        }
        const float bb = bqe[j];
        const float av[4] = {a0 + bb, a1 + bb, a2 + bb, a3 + bb};
        #pragma unroll
        for (int i = 0; i < 4; ++i) {
            const int n = base + r0 + i;
            if (n < n_nodes) qwe[(size_t)n * DEA + j] = av[i];
        }
    }
}

// ---------------------------------------------------------------------------
// CSR build over dst: histogram -> 3-pass multi-block scan -> scatter
// ---------------------------------------------------------------------------
__global__ __launch_bounds__(256) void hist_kernel(
    const int* __restrict__ dst, int* __restrict__ counts, int n_edges, int n_nodes)
{
    const int eid = blockIdx.x * 256 + threadIdx.x;
    if (eid >= n_edges) return;
    int d = dst[eid];
    d = (d < 0) ? 0 : ((d >= n_nodes) ? n_nodes - 1 : d);
    atomicAdd(&counts[d], 1);
}

__global__ __launch_bounds__(256) void scan_pass1_kernel(
    const int* __restrict__ counts, int* __restrict__ row_ptr,
    int* __restrict__ blksum, int n)
{
    const int tid = threadIdx.x;
    const int lane = tid & 63;
    const int base = blockIdx.x * 1024 + tid * 4;
    int c0 = 0, c1 = 0, c2 = 0, c3 = 0;
    if (base + 3 < n) {
        const int4 v = *(const int4*)&counts[base];
        c0 = v.x; c1 = v.y; c2 = v.z; c3 = v.w;
    } else {
        if (base + 0 < n) c0 = counts[base + 0];
        if (base + 1 < n) c1 = counts[base + 1];
        if (base + 2 < n) c2 = counts[base + 2];
        if (base + 3 < n) c3 = counts[base + 3];
    }
    const int tsum = c0 + c1 + c2 + c3;
    int incl = tsum;
    #pragma unroll
    for (int off = 1; off < 64; off <<= 1) {
        const int t = __shfl_up(incl, off, 64);
        if (lane >= off) incl += t;
    }
    __shared__ int wsum[4];
    const int wv = tid >> 6;
    if (lane == 63) wsum[wv] = incl;
    __syncthreads();
    int woff = 0;
    #pragma unroll
    for (int i = 0; i < 4; ++i) if (i < wv) woff += wsum[i];
    const int excl = woff + incl - tsum;
    if (base + 3 < n) {
        int4 o;
        o.x = excl; o.y = excl + c0; o.z = excl + c0 + c1; o.w = excl + c0 + c1 + c2;
        *(int4*)&row_ptr[base] = o;
    } else {
        if (base + 0 < n) row_ptr[base + 0] = excl;
        if (base + 1 < n) row_ptr[base + 1] = excl + c0;
        if (base + 2 < n) row_ptr[base + 2] = excl + c0 + c1;
        if (base + 3 < n) row_ptr[base + 3] = excl + c0 + c1 + c2;
    }
    if (tid == 255) blksum[blockIdx.x] = woff + incl;
}

__global__ __launch_bounds__(64) void scan_pass2_kernel(
    const int* __restrict__ blksum, int* __restrict__ blkoff,
    int* __restrict__ row_ptr, int nb, int n)
{
    const int lane = threadIdx.x;
    int carry = 0;
    for (int base = 0; base < nb; base += 64) {
        const int idx = base + lane;
        const int v = (idx < nb) ? blksum[idx] : 0;
        int incl = v;
        #pragma unroll
        for (int off = 1; off < 64; off <<= 1) {
            const int t = __shfl_up(incl, off, 64);
            if (lane >= off) incl += t;
        }
        if (idx < nb) blkoff[idx] = carry + incl - v;
        carry += __shfl(incl, 63, 64);
    }
    if (lane == 0) row_ptr[n] = carry;
}

__global__ __launch_bounds__(256) void scan_pass3_kernel(
    int* __restrict__ row_ptr, int* __restrict__ cursor,
    const int* __restrict__ blkoff, int n)
{
    const int base = blockIdx.x * 1024 + threadIdx.x * 4;
    const int off = blkoff[blockIdx.x];
    if (base + 3 < n) {
        int4 v = *(const int4*)&row_ptr[base];
        v.x += off; v.y += off; v.z += off; v.w += off;
        *(int4*)&row_ptr[base] = v;
        *(int4*)&cursor[base]  = v;
    } else {
        #pragma unroll
        for (int i = 0; i < 4; ++i) {
            if (base + i < n) {
                const int v = row_ptr[base + i] + off;
                row_ptr[base + i] = v;
                cursor[base + i]  = v;
            }
        }
    }
}

__global__ __launch_bounds__(256) void scatter_kernel(
    const int* __restrict__ dst, const int* __restrict__ src,
    int* __restrict__ cursor, int2* __restrict__ pair, int n_edges, int n_nodes)
{
    const int eid = blockIdx.x * 256 + threadIdx.x;
    if (eid >= n_edges) return;
    int d = dst[eid];
    d = (d < 0) ? 0 : ((d >= n_nodes) ? n_nodes - 1 : d);
    int s = src[eid];
    s = (s < 0) ? 0 : ((s >= n_nodes) ? n_nodes - 1 : s);
    const int pos = atomicAdd(&cursor[d], 1);
    pair[pos] = make_int2(eid, s);
}

// ---------------------------------------------------------------------------
// Fused aggregation v7: one wave per dst node; 8 edge-groups x 8 lanes;
// 16 edges per iteration as two STATIC halves A,B — all 6 gathers issue
// together at iteration top (pairs prefetched last iteration), so the
// serial chain for deg<=16 nodes is one kv round-trip.
//   score = q.k[src] + qwe.ea ;  msg = sum p*v[src] ; sea = sum p*ea
//   out   = relu(skip + (msg + sea@We)/l)
// ---------------------------------------------------------------------------
__global__ __launch_bounds__(256) void fused_edge_kernel(
    const float* __restrict__ q, const float* __restrict__ qwe,
    const unsigned short* __restrict__ kvb, const float* __restrict__ ea,
    const float* __restrict__ we, const float* __restrict__ aggskip,
    const int* __restrict__ row_ptr, const int2* __restrict__ pair,
    float* __restrict__ h_out, int n_nodes)
{
    __shared__ float lw[DEA * DIM];   // 8 KB, We row-major [32][64]
    __shared__ float lsea[4][36];     // per-wave merged sea
    __shared__ float lmsg[4][72];     // per-wave merged msg
    const int tid = threadIdx.x;
    {
        const float4* s4 = (const float4*)we;
        float4* d4 = (float4*)lw;
        d4[tid] = s4[tid];
        d4[tid + 256] = s4[tid + 256];
    }
    __syncthreads();

    const int wave = tid >> 6;
    const int lane = tid & 63;
    const int g = lane >> 3;          // edge group 0..7
    const int j = lane & 7;           // channel slot: ch [j*8, j*8+8)
    const int node = blockIdx.x * 4 + wave;
    if (node >= n_nodes) return;

    const float4 qa  = *(const float4*)&q[(size_t)node * DIM + j * 8];
    const float4 qb  = *(const float4*)&q[(size_t)node * DIM + j * 8 + 4];
    const float4 qw4 = *(const float4*)&qwe[(size_t)node * DEA + j * 4];
    const int beg = row_ptr[node], end = row_ptr[node + 1];

    float m = -3.0e38f, l = 0.f;
    float4 msgA = make_float4(0.f, 0.f, 0.f, 0.f);
    float4 msgB = make_float4(0.f, 0.f, 0.f, 0.f);
    float4 sea  = make_float4(0.f, 0.f, 0.f, 0.f);

    if (beg < end) {
        const int last = end - 1;
        int2 prA = pair[(beg + g     < end) ? (beg + g)     : last];
        int2 prB = pair[(beg + 8 + g < end) ? (beg + 8 + g) : last];

        for (int i0 = beg; i0 < end; i0 += 16) {
            // ---- issue all gathers for both halves ----
            const unsigned short* kpA = &kvb[(size_t)prA.y * 128];
            const uint4 krA  = *(const uint4*)&kpA[j * 8];
            const uint4 vrA  = *(const uint4*)&kpA[64 + j * 8];
            const float4 eaA = *(const float4*)&ea[(size_t)prA.x * DEA + j * 4];
            const unsigned short* kpB = &kvb[(size_t)prB.y * 128];
            const uint4 krB  = *(const uint4*)&kpB[j * 8];
            const uint4 vrB  = *(const uint4*)&kpB[64 + j * 8];
            const float4 eaB = *(const float4*)&ea[(size_t)prB.x * DEA + j * 4];

            // ---- prefetch next iteration's pairs (overlaps compute) ----
            if (i0 + 16 < end) {
                prA = pair[(i0 + 16 + g < end) ? (i0 + 16 + g) : last];
                prB = pair[(i0 + 24 + g < end) ? (i0 + 24 + g) : last];
            }

            // ---- half A ----
            {
                const bool act = (i0 + g) < end;
                float t0 = fmaf(qa.x, bflo(krA.x), qw4.x * eaA.x);
                t0 = fmaf(qa.y, bfhi(krA.x), t0);
                t0 = fmaf(qa.z, bflo(krA.y), t0);
                t0 = fmaf(qa.w, bfhi(krA.y), t0);
                t0 = fmaf(qw4.z, eaA.z, t0);
                float t1 = fmaf(qb.x, bflo(krA.z), qw4.y * eaA.y);
                t1 = fmaf(qb.y, bfhi(krA.z), t1);
                t1 = fmaf(qb.z, bflo(krA.w), t1);
                t1 = fmaf(qb.w, bfhi(krA.w), t1);
                t1 = fmaf(qw4.w, eaA.w, t1);
                float t = t0 + t1;
                t += __shfl_xor(t, 1, 64);
                t += __shfl_xor(t, 2, 64);
                t += __shfl_xor(t, 4, 64);
                const float score = act ? t : -3.0e38f;
                const float mn = fmaxf(m, score);
                const float p  = act ? __expf(score - mn) : 0.f;
                const float sc = __expf(m - mn);
                l = l * sc + p;
                msgA.x = fmaf(p, bflo(vrA.x), msgA.x * sc);
                msgA.y = fmaf(p, bfhi(vrA.x), msgA.y * sc);
                msgA.z = fmaf(p, bflo(vrA.y), msgA.z * sc);
                msgA.w = fmaf(p, bfhi(vrA.y), msgA.w * sc);
                msgB.x = fmaf(p, bflo(vrA.z), msgB.x * sc);
                msgB.y = fmaf(p, bfhi(vrA.z), msgB.y * sc);
                msgB.z = fmaf(p, bflo(vrA.w), msgB.z * sc);
                msgB.w = fmaf(p, bfhi(vrA.w), msgB.w * sc);
                sea.x = fmaf(p, eaA.x, sea.x * sc);
                sea.y = fmaf(p, eaA.y, sea.y * sc);
                sea.z = fmaf(p, eaA.z, sea.z * sc);
                sea.w = fmaf(p, eaA.w, sea.w * sc);
                m = mn;
            }
            // ---- half B ----
            {
                const bool act = (i0 + 8 + g) < end;
                float t0 = fmaf(qa.x, bflo(krB.x), qw4.x * eaB.x);
                t0 = fmaf(qa.y, bfhi(krB.x), t0);
                t0 = fmaf(qa.z, bflo(krB.y), t0);
                t0 = fmaf(qa.w, bfhi(krB.y), t0);
                t0 = fmaf(qw4.z, eaB.z, t0);
                float t1 = fmaf(qb.x, bflo(krB.z), qw4.y * eaB.y);
                t1 = fmaf(qb.y, bfhi(krB.z), t1);
                t1 = fmaf(qb.z, bflo(krB.w), t1);
                t1 = fmaf(qb.w, bfhi(krB.w), t1);
                t1 = fmaf(qw4.w, eaB.w, t1);
                float t = t0 + t1;
                t += __shfl_xor(t, 1, 64);
                t += __shfl_xor(t, 2, 64);
                t += __shfl_xor(t, 4, 64);
                const float score = act ? t : -3.0e38f;
                const float mn = fmaxf(m, score);
                const float p  = act ? __expf(score - mn) : 0.f;
                const float sc = __expf(m - mn);
                l = l * sc + p;
                msgA.x = fmaf(p, bflo(vrB.x), msgA.x * sc);
                msgA.y = fmaf(p, bfhi(vrB.x), msgA.y * sc);
                msgA.z = fmaf(p, bflo(vrB.y), msgA.z * sc);
                msgA.w = fmaf(p, bfhi(vrB.y), msgA.w * sc);
                msgB.x = fmaf(p, bflo(vrB.z), msgB.x * sc);
                msgB.y = fmaf(p, bfhi(vrB.z), msgB.y * sc);
                msgB.z = fmaf(p, bflo(vrB.w), msgB.z * sc);
                msgB.w = fmaf(p, bfhi(vrB.w), msgB.w * sc);
                sea.x = fmaf(p, eaB.x, sea.x * sc);
                sea.y = fmaf(p, eaB.y, sea.y * sc);
                sea.z = fmaf(p, eaB.z, sea.z * sc);
                sea.w = fmaf(p, eaB.w, sea.w * sc);
                m = mn;
            }
        }
    }

    // merge the 8 groups over g bits (xor 8, 16, 32)
    #pragma unroll
    for (int off = 8; off <= 32; off <<= 1) {
        const float m2 = __shfl_xor(m, off, 64);
        const float l2 = __shfl_xor(l, off, 64);
        float4 a2, b2, s2;
        a2.x = __shfl_xor(msgA.x, off, 64); a2.y = __shfl_xor(msgA.y, off, 64);
        a2.z = __shfl_xor(msgA.z, off, 64); a2.w = __shfl_xor(msgA.w, off, 64);
        b2.x = __shfl_xor(msgB.x, off, 64); b2.y = __shfl_xor(msgB.y, off, 64);
        b2.z = __shfl_xor(msgB.z, off, 64); b2.w = __shfl_xor(msgB.w, off, 64);
        s2.x = __shfl_xor(sea.x, off, 64);  s2.y = __shfl_xor(sea.y, off, 64);
        s2.z = __shfl_xor(sea.z, off, 64);  s2.w = __shfl_xor(sea.w, off, 64);
        const float mn = fmaxf(m, m2);
        const float w1 = __expf(m - mn);
        const float w2 = __expf(m2 - mn);
        l = l * w1 + l2 * w2;
        msgA.x = msgA.x * w1 + a2.x * w2; msgA.y = msgA.y * w1 + a2.y * w2;
        msgA.z = msgA.z * w1 + a2.z * w2; msgA.w = msgA.w * w1 + a2.w * w2;
        msgB.x = msgB.x * w1 + b2.x * w2; msgB.y = msgB.y * w1 + b2.y * w2;
        msgB.z = msgB.z * w1 + b2.z * w2; msgB.w = msgB.w * w1 + b2.w * w2;
        sea.x = sea.x * w1 + s2.x * w2;   sea.y = sea.y * w1 + s2.y * w2;
        sea.z = sea.z * w1 + s2.z * w2;   sea.w = sea.w * w1 + s2.w * w2;
        m = mn;
    }

    // stage merged state in per-wave LDS (any one group; use g==0)
    if (g == 0) {
        *(float4*)&lsea[wave][j * 4]     = sea;
        *(float4*)&lmsg[wave][j * 8]     = msgA;
        *(float4*)&lmsg[wave][j * 8 + 4] = msgB;
    }
    const float inv = (l > 0.f) ? (1.f / l) : 0.f;

    // epilogue: lane handles output channel = lane
    float e = 0.f;
    #pragma unroll 8
    for (int j2 = 0; j2 < DEA; ++j2)
        e = fmaf(lsea[wave][j2], lw[j2 * DIM + lane], e);
    const float msgc = lmsg[wave][lane];
    const float sk = aggskip[(size_t)node * DIM + lane];
    h_out[(size_t)node * DIM + lane] = fmaxf(fmaf(msgc + e, inv, sk), 0.f);
}

// ---------------------------------------------------------------------------
// Final: out = relu(concat(h1,h2) @ skip_w + skip_b), K=128
// ---------------------------------------------------------------------------
__global__ __launch_bounds__(256) void final_kernel(
    const float* __restrict__ h1, const float* __restrict__ h2,
    const float* __restrict__ w, const float* __restrict__ b,
    float* __restrict__ out, int n_nodes)
{
    __shared__ float lw[128 * DIM];   // 32 KB
    __shared__ float lx[16][128];     // 8 KB
    const int tid = threadIdx.x;
    {
        const float4* s4 = (const float4*)w;
        float4* d4 = (float4*)lw;
        #pragma unroll
        for (int i = 0; i < 8; ++i) d4[tid + i * 256] = s4[tid + i * 256];
    }
    const int base = blockIdx.x * 16;
    {
        #pragma unroll
        for (int t = 0; t < 2; ++t) {
            const int f = tid + t * 256;
            const int r = f >> 5;
            const int cf = f & 31;
            const int n = base + r;
            float4 val = make_float4(0.f, 0.f, 0.f, 0.f);
            if (n < n_nodes) {
                if (cf < 16) val = *(const float4*)&h1[(size_t)n * DIM + cf * 4];
                else         val = *(const float4*)&h2[(size_t)n * DIM + (cf - 16) * 4];
            }
            *(float4*)&lx[r][cf * 4] = val;
        }
    }
    __syncthreads();

    const int oc = tid & 63;
    const int nl = tid >> 6;
    float acc[4] = {0, 0, 0, 0};
    #pragma unroll 8
    for (int kk = 0; kk < 128; ++kk) {
        const float wv = lw[kk * DIM + oc];
        #pragma unroll
        for (int r = 0; r < 4; ++r)
            acc[r] = fmaf(lx[nl * 4 + r][kk], wv, acc[r]);
    }
    const float bv = b[oc];
    #pragma unroll
    for (int r = 0; r < 4; ++r) {
        const int n = base + nl * 4 + r;
        if (n < n_nodes) out[(size_t)n * DIM + oc] = fmaxf(acc[r] + bv, 0.f);
    }
}

// ---------------------------------------------------------------------------
extern "C" void kernel_launch(void* const* d_in, const int* in_sizes, int n_in,
                              void* d_out, int out_size, void* d_ws, size_t ws_size,
                              hipStream_t stream)
{
    const float* x     = (const float*)d_in[0];
    const int*   ei    = (const int*)d_in[1];
    const float* eattr = (const float*)d_in[2];
    const float *q1w = (const float*)d_in[3],  *q1b = (const float*)d_in[4];
    const float *k1w = (const float*)d_in[5],  *k1b = (const float*)d_in[6];
    const float *v1w = (const float*)d_in[7],  *v1b = (const float*)d_in[8];
    const float *e1w = (const float*)d_in[9];
    const float *s1w = (const float*)d_in[10], *s1b = (const float*)d_in[11];
    const float *q2w = (const float*)d_in[12], *q2b = (const float*)d_in[13];
    const float *k2w = (const float*)d_in[14], *k2b = (const float*)d_in[15];
    const float *v2w = (const float*)d_in[16], *v2b = (const float*)d_in[17];
    const float *e2w = (const float*)d_in[18];
    const float *s2w = (const float*)d_in[19], *s2b = (const float*)d_in[20];
    const float *skw = (const float*)d_in[21], *skb = (const float*)d_in[22];

    const int N = in_sizes[0] / DIM;
    const int E = in_sizes[1] / 2;
    const int* src = ei;
    const int* dst = ei + E;

    float* ws = (float*)d_ws;
    const size_t nf = (size_t)N * DIM;
    float* q    = ws;                          // nf
    unsigned short* kvb = (unsigned short*)(q + nf);  // N*128 ushorts = nf floats
    float* agg  = q + 2 * nf;                  // nf
    float* h1   = agg + nf;                    // nf
    float* h2   = h1 + nf;                     // nf
    float* qwe  = h2 + nf;                     // 32*N
    int2* pair    = (int2*)(qwe + (size_t)DEA * N);    // E int2
    int* cursor   = (int*)(pair + E);                  // N
    int* row_ptr  = cursor + ((N + 3) & ~3);           // N+1
    const int nb  = (N + 1023) / 1024;
    int* blksum   = row_ptr + ((N + 4) & ~3);          // nb
    int* blkoff   = blksum + ((nb + 3) & ~3);          // nb
    float* wqeW1  = (float*)(blkoff + ((nb + 3) & ~3));// 2048
    float* bqe1   = wqeW1 + 64 * 32;                   // 32
    float* wqeW2  = bqe1 + 32;                         // 2048
    float* bqe2   = wqeW2 + 64 * 32;                   // 32

    const int nblk = (N + 31) / 32;
    const int eblk = (E + 255) / 256;
    const int fblk = (N + 3) / 4;
    const int finblk = (N + 15) / 16;

    // ---------------- CSR over dst + combined score weights ----------------
    hipMemsetAsync(cursor, 0, (size_t)N * sizeof(int), stream);
    hist_kernel<<<eblk, 256, 0, stream>>>(dst, cursor, E, N);
    scan_pass1_kernel<<<nb, 256, 0, stream>>>(cursor, row_ptr, blksum, N);
    scan_pass2_kernel<<<1, 64, 0, stream>>>(blksum, blkoff, row_ptr, nb, N);
    scan_pass3_kernel<<<nb, 256, 0, stream>>>(row_ptr, cursor, blkoff, N);
    scatter_kernel<<<eblk, 256, 0, stream>>>(dst, src, cursor, pair, E, N);
    wqe_prep_kernel<<<2, 256, 0, stream>>>(q1w, q1b, e1w, q2w, q2b, e2w,
                                           wqeW1, bqe1, wqeW2, bqe2);

    // ---------------- layer 1 ----------------
    node_lin_kernel<<<nblk, 256, 0, stream>>>(x, q1w, q1b, k1w, k1b, v1w, v1b,
                                              s1w, s1b, wqeW1, bqe1,
                                              q, kvb, agg, qwe, N);
    fused_edge_kernel<<<fblk, 256, 0, stream>>>(q, qwe, kvb, eattr, e1w, agg,
                                                row_ptr, pair, h1, N);

    // ---------------- layer 2 ----------------
    node_lin_kernel<<<nblk, 256, 0, stream>>>(h1, q2w, q2b, k2w, k2b, v2w, v2b,
                                              s2w, s2b, wqeW2, bqe2,
                                              q, kvb, agg, qwe, N);
    fused_edge_kernel<<<fblk, 256, 0, stream>>>(q, qwe, kvb, eattr, e2w, agg,
                                                row_ptr, pair, h2, N);

    // ---------------- final skip MLP ----------------
    final_kernel<<<finblk, 256, 0, stream>>>(h1, h2, skw, skb, (float*)d_out, N);
}

// Round 11
// 344.576 us; speedup vs baseline: 1.0462x; 1.0419x over previous
//
#include <hip/hip_runtime.h>

#define DIM 64
#define DEA 32

__device__ __forceinline__ unsigned short f2bf(float f) {
    const unsigned u = __float_as_uint(f);
    return (unsigned short)((u + 0x7FFFu + ((u >> 16) & 1u)) >> 16);   // RNE
}
__device__ __forceinline__ float bflo(unsigned u) { return __uint_as_float(u << 16); }
__device__ __forceinline__ float bfhi(unsigned u) { return __uint_as_float(u & 0xFFFF0000u); }

// ---------------------------------------------------------------------------
// One-time: combined score weight  M = (Wq @ We^T)*0.125  [64][32],
// bqe = (bq @ We^T)*0.125.  (score scale folded in; exact pow2)
// ---------------------------------------------------------------------------
__global__ __launch_bounds__(256) void wqe_prep_kernel(
    const float* __restrict__ wq1, const float* __restrict__ bq1, const float* __restrict__ we1,
    const float* __restrict__ wq2, const float* __restrict__ bq2, const float* __restrict__ we2,
    float* __restrict__ w1out, float* __restrict__ b1out,
    float* __restrict__ w2out, float* __restrict__ b2out)
{
    const float* wq = blockIdx.x ? wq2 : wq1;
    const float* bq = blockIdx.x ? bq2 : bq1;
    const float* we = blockIdx.x ? we2 : we1;
    float* wout = blockIdx.x ? w2out : w1out;
    float* bout = blockIdx.x ? b2out : b1out;

    __shared__ float lq[64 * 64];
    __shared__ float lweT[64 * 33];
    const int tid = threadIdx.x;
    {
        const float4* s4 = (const float4*)wq;
        float4* d4 = (float4*)lq;
        #pragma unroll
        for (int i = 0; i < 4; ++i) d4[tid + i * 256] = s4[tid + i * 256];
        const float4* e4 = (const float4*)we;
        #pragma unroll
        for (int t = 0; t < 2; ++t) {
            const int f = tid + t * 256;
            const int j = f >> 4;
            const int o4 = (f & 15) * 4;
            const float4 v = e4[f];
            lweT[(o4 + 0) * 33 + j] = v.x;
            lweT[(o4 + 1) * 33 + j] = v.y;
            lweT[(o4 + 2) * 33 + j] = v.z;
            lweT[(o4 + 3) * 33 + j] = v.w;
        }
    }
    __syncthreads();
    const int j = tid & 31;
    const int c0 = (tid >> 5) * 8;
    for (int c = c0; c < c0 + 8; ++c) {
        float acc = 0.f;
        #pragma unroll 8
        for (int o = 0; o < 64; ++o) acc = fmaf(lq[c * 64 + o], lweT[o * 33 + j], acc);
        wout[c * 32 + j] = acc * 0.125f;
    }
    if (tid < 32) {
        float acc = 0.f;
        #pragma unroll 8
        for (int o = 0; o < 64; ++o) acc = fmaf(bq[o], lweT[o * 33 + tid], acc);
        bout[tid] = acc * 0.125f;
    }
}

// ---------------------------------------------------------------------------
// Node linear v3: 32 nodes/block; q scaled by 0.125; k,v as bf16.
// ---------------------------------------------------------------------------
__global__ __launch_bounds__(256) void node_lin_kernel(
    const float* __restrict__ x,
    const float* __restrict__ wq, const float* __restrict__ bq,
    const float* __restrict__ wk, const float* __restrict__ bk,
    const float* __restrict__ wv, const float* __restrict__ bv,
    const float* __restrict__ wsk, const float* __restrict__ bsk,
    const float* __restrict__ wqe_w, const float* __restrict__ bqe,
    float* __restrict__ q, unsigned short* __restrict__ kvb,
    float* __restrict__ agg, float* __restrict__ qwe, int n_nodes)
{
    __shared__ float lw[16 * 256];
    __shared__ float lxT[64 * 36];
    __shared__ float lwqe[64 * 32];
    const int tid = threadIdx.x;
    const int base = blockIdx.x * 32;

    {
        #pragma unroll
        for (int t = 0; t < 2; ++t) {
            const int f = tid + t * 256;
            const int node = f >> 4;
            const int c4 = (f & 15) * 4;
            const int n = base + node;
            float4 val = make_float4(0.f, 0.f, 0.f, 0.f);
            if (n < n_nodes) val = *(const float4*)&x[(size_t)n * DIM + c4];
            lxT[(c4 + 0) * 36 + node] = val.x;
            lxT[(c4 + 1) * 36 + node] = val.y;
            lxT[(c4 + 2) * 36 + node] = val.z;
            lxT[(c4 + 3) * 36 + node] = val.w;
        }
        const float4* s4 = (const float4*)wqe_w;
        float4* d4 = (float4*)lwqe;
        d4[tid] = s4[tid];
        d4[tid + 256] = s4[tid + 256];
    }

    const int m = tid >> 6;
    const int oc = tid & 63;
    const float* wsrc = (m == 0) ? wq : (m == 1) ? wk : (m == 2) ? wv : wsk;
    const float bias = ((m == 0) ? bq : (m == 1) ? bk : (m == 2) ? bv : bsk)[oc];

    float acc[32];
    #pragma unroll
    for (int r = 0; r < 32; ++r) acc[r] = 0.f;

    for (int kc = 0; kc < 4; ++kc) {
        __syncthreads();
        #pragma unroll
        for (int i = 0; i < 4; ++i) {
            const int f = oc + i * 64;
            const int kk = f >> 4;
            const int c4 = (f & 15) * 4;
            const float4 w4 = *(const float4*)&wsrc[(size_t)(kc * 16 + kk) * DIM + c4];
            *(float4*)&lw[kk * 256 + m * 64 + c4] = w4;
        }
        __syncthreads();
        #pragma unroll
        for (int kk = 0; kk < 16; ++kk) {
            const float wv_ = lw[kk * 256 + tid];
            const float* xrow = &lxT[(kc * 16 + kk) * 36];
            #pragma unroll
            for (int r4 = 0; r4 < 8; ++r4) {
                const float4 xv = *(const float4*)&xrow[r4 * 4];
                acc[r4 * 4 + 0] = fmaf(xv.x, wv_, acc[r4 * 4 + 0]);
                acc[r4 * 4 + 1] = fmaf(xv.y, wv_, acc[r4 * 4 + 1]);
                acc[r4 * 4 + 2] = fmaf(xv.z, wv_, acc[r4 * 4 + 2]);
                acc[r4 * 4 + 3] = fmaf(xv.w, wv_, acc[r4 * 4 + 3]);
            }
        }
    }

    #pragma unroll
    for (int r = 0; r < 32; ++r) {
        const int n = base + r;
        if (n < n_nodes) {
            const float val = acc[r] + bias;
            if (m == 0)      q[(size_t)n * DIM + oc]            = val * 0.125f;
            else if (m == 1) kvb[(size_t)n * 128 + oc]          = f2bf(val);
            else if (m == 2) kvb[(size_t)n * 128 + 64 + oc]     = f2bf(val);
            else             agg[(size_t)n * DIM + oc]          = val;   // root skip
        }
    }

    // qwe phase (weights pre-scaled by 0.125)
    {
        const int j = tid & 31;
        const int r0 = (tid >> 5) * 4;
        float a0 = 0.f, a1 = 0.f, a2 = 0.f, a3 = 0.f;
        #pragma unroll 8
        for (int c = 0; c < DIM; ++c) {
            const float wv_ = lwqe[c * 32 + j];
            const float4 xv = *(const float4*)&lxT[c * 36 + r0];
            a0 = fmaf(xv.x, wv_, a0);
            a1 = fmaf(xv.y, wv_, a1);
            a2 = fmaf(xv.z, wv_, a2);
            a3 = fmaf(xv.w, wv_, a3);
        }
        const float bb = bqe[j];
        const float av[4] = {a0 + bb, a1 + bb, a2 + bb, a3 + bb};
        #pragma unroll
        for (int i = 0; i < 4; ++i) {
            const int n = base + r0 + i;
            if (n < n_nodes) qwe[(size_t)n * DEA + j] = av[i];
        }
    }
}

// ---------------------------------------------------------------------------
// CSR build over dst: histogram -> 3-pass multi-block scan -> scatter
// ---------------------------------------------------------------------------
__global__ __launch_bounds__(256) void hist_kernel(
    const int* __restrict__ dst, int* __restrict__ counts, int n_edges, int n_nodes)
{
    const int eid = blockIdx.x * 256 + threadIdx.x;
    if (eid >= n_edges) return;
    int d = dst[eid];
    d = (d < 0) ? 0 : ((d >= n_nodes) ? n_nodes - 1 : d);
    atomicAdd(&counts[d], 1);
}

__global__ __launch_bounds__(256) void scan_pass1_kernel(
    const int* __restrict__ counts, int* __restrict__ row_ptr,
    int* __restrict__ blksum, int n)
{
    const int tid = threadIdx.x;
    const int lane = tid & 63;
    const int base = blockIdx.x * 1024 + tid * 4;
    int c0 = 0, c1 = 0, c2 = 0, c3 = 0;
    if (base + 3 < n) {
        const int4 v = *(const int4*)&counts[base];
        c0 = v.x; c1 = v.y; c2 = v.z; c3 = v.w;
    } else {
        if (base + 0 < n) c0 = counts[base + 0];
        if (base + 1 < n) c1 = counts[base + 1];
        if (base + 2 < n) c2 = counts[base + 2];
        if (base + 3 < n) c3 = counts[base + 3];
    }
    const int tsum = c0 + c1 + c2 + c3;
    int incl = tsum;
    #pragma unroll
    for (int off = 1; off < 64; off <<= 1) {
        const int t = __shfl_up(incl, off, 64);
        if (lane >= off) incl += t;
    }
    __shared__ int wsum[4];
    const int wv = tid >> 6;
    if (lane == 63) wsum[wv] = incl;
    __syncthreads();
    int woff = 0;
    #pragma unroll
    for (int i = 0; i < 4; ++i) if (i < wv) woff += wsum[i];
    const int excl = woff + incl - tsum;
    if (base + 3 < n) {
        int4 o;
        o.x = excl; o.y = excl + c0; o.z = excl + c0 + c1; o.w = excl + c0 + c1 + c2;
        *(int4*)&row_ptr[base] = o;
    } else {
        if (base + 0 < n) row_ptr[base + 0] = excl;
        if (base + 1 < n) row_ptr[base + 1] = excl + c0;
        if (base + 2 < n) row_ptr[base + 2] = excl + c0 + c1;
        if (base + 3 < n) row_ptr[base + 3] = excl + c0 + c1 + c2;
    }
    if (tid == 255) blksum[blockIdx.x] = woff + incl;
}

__global__ __launch_bounds__(64) void scan_pass2_kernel(
    const int* __restrict__ blksum, int* __restrict__ blkoff,
    int* __restrict__ row_ptr, int nb, int n)
{
    const int lane = threadIdx.x;
    int carry = 0;
    for (int base = 0; base < nb; base += 64) {
        const int idx = base + lane;
        const int v = (idx < nb) ? blksum[idx] : 0;
        int incl = v;
        #pragma unroll
        for (int off = 1; off < 64; off <<= 1) {
            const int t = __shfl_up(incl, off, 64);
            if (lane >= off) incl += t;
        }
        if (idx < nb) blkoff[idx] = carry + incl - v;
        carry += __shfl(incl, 63, 64);
    }
    if (lane == 0) row_ptr[n] = carry;
}

__global__ __launch_bounds__(256) void scan_pass3_kernel(
    int* __restrict__ row_ptr, int* __restrict__ cursor,
    const int* __restrict__ blkoff, int n)
{
    const int base = blockIdx.x * 1024 + threadIdx.x * 4;
    const int off = blkoff[blockIdx.x];
    if (base + 3 < n) {
        int4 v = *(const int4*)&row_ptr[base];
        v.x += off; v.y += off; v.z += off; v.w += off;
        *(int4*)&row_ptr[base] = v;
        *(int4*)&cursor[base]  = v;
    } else {
        #pragma unroll
        for (int i = 0; i < 4; ++i) {
            if (base + i < n) {
                const int v = row_ptr[base + i] + off;
                row_ptr[base + i] = v;
                cursor[base + i]  = v;
            }
        }
    }
}

__global__ __launch_bounds__(256) void scatter_kernel(
    const int* __restrict__ dst, const int* __restrict__ src,
    int* __restrict__ cursor, int2* __restrict__ pair, int n_edges, int n_nodes)
{
    const int eid = blockIdx.x * 256 + threadIdx.x;
    if (eid >= n_edges) return;
    int d = dst[eid];
    d = (d < 0) ? 0 : ((d >= n_nodes) ? n_nodes - 1 : d);
    int s = src[eid];
    s = (s < 0) ? 0 : ((s >= n_nodes) ? n_nodes - 1 : s);
    const int pos = atomicAdd(&cursor[d], 1);
    pair[pos] = make_int2(eid, s);
}

// ---------------------------------------------------------------------------
// Fused aggregation (R8 optimum): one wave per dst node; 8 edge-groups x 8
// lanes; lane owns 8 channels; single prefetched pair; all-lane LDS epilogue.
//   score = q.k[src] + qwe.ea ;  msg = sum p*v[src] ; sea = sum p*ea
//   out   = relu(skip + (msg + sea@We)/l)
// ---------------------------------------------------------------------------
__global__ __launch_bounds__(256) void fused_edge_kernel(
    const float* __restrict__ q, const float* __restrict__ qwe,
    const unsigned short* __restrict__ kvb, const float* __restrict__ ea,
    const float* __restrict__ we, const float* __restrict__ aggskip,
    const int* __restrict__ row_ptr, const int2* __restrict__ pair,
    float* __restrict__ h_out, int n_nodes)
{
    __shared__ float lw[DEA * DIM];   // 8 KB, We row-major [32][64]
    __shared__ float lsea[4][36];     // per-wave merged sea
    __shared__ float lmsg[4][72];     // per-wave merged msg
    const int tid = threadIdx.x;
    {
        const float4* s4 = (const float4*)we;
        float4* d4 = (float4*)lw;
        d4[tid] = s4[tid];
        d4[tid + 256] = s4[tid + 256];
    }
    __syncthreads();

    const int wave = tid >> 6;
    const int lane = tid & 63;
    const int g = lane >> 3;          // edge group 0..7
    const int j = lane & 7;           // channel slot: ch [j*8, j*8+8)
    const int node = blockIdx.x * 4 + wave;
    if (node >= n_nodes) return;

    const float4 qa  = *(const float4*)&q[(size_t)node * DIM + j * 8];
    const float4 qb  = *(const float4*)&q[(size_t)node * DIM + j * 8 + 4];
    const float4 qw4 = *(const float4*)&qwe[(size_t)node * DEA + j * 4];
    const int beg = row_ptr[node], end = row_ptr[node + 1];

    float m = -3.0e38f, l = 0.f;
    float4 msgA = make_float4(0.f, 0.f, 0.f, 0.f);
    float4 msgB = make_float4(0.f, 0.f, 0.f, 0.f);
    float4 sea  = make_float4(0.f, 0.f, 0.f, 0.f);

    if (beg < end) {
        int2 pr = pair[(beg + g < end) ? (beg + g) : (end - 1)];
        for (int i0 = beg; i0 < end; i0 += 8) {
            const bool act = (i0 + g) < end;
            const int eid = pr.x;
            const int s   = pr.y;
            const unsigned short* kvp = &kvb[(size_t)s * 128];
            const uint4 kraw = *(const uint4*)&kvp[j * 8];         // 8 bf16 k
            const uint4 vraw = *(const uint4*)&kvp[64 + j * 8];    // 8 bf16 v
            const float4 ea4 = *(const float4*)&ea[(size_t)eid * DEA + j * 4];
            const int inext = i0 + 8 + g;
            if (inext < end) pr = pair[inext];   // prefetch next group pair

            float t0 = fmaf(qa.x, bflo(kraw.x), qw4.x * ea4.x);
            t0 = fmaf(qa.y, bfhi(kraw.x), t0);
            t0 = fmaf(qa.z, bflo(kraw.y), t0);
            t0 = fmaf(qa.w, bfhi(kraw.y), t0);
            t0 = fmaf(qw4.z, ea4.z, t0);
            float t1 = fmaf(qb.x, bflo(kraw.z), qw4.y * ea4.y);
            t1 = fmaf(qb.y, bfhi(kraw.z), t1);
            t1 = fmaf(qb.z, bflo(kraw.w), t1);
            t1 = fmaf(qb.w, bfhi(kraw.w), t1);
            t1 = fmaf(qw4.w, ea4.w, t1);
            float t = t0 + t1;
            t += __shfl_xor(t, 1, 64);
            t += __shfl_xor(t, 2, 64);
            t += __shfl_xor(t, 4, 64);
            const float score = act ? t : -3.0e38f;

            const float mn = fmaxf(m, score);
            const float p  = act ? __expf(score - mn) : 0.f;
            const float sc = __expf(m - mn);
            l = l * sc + p;
            msgA.x = fmaf(p, bflo(vraw.x), msgA.x * sc);
            msgA.y = fmaf(p, bfhi(vraw.x), msgA.y * sc);
            msgA.z = fmaf(p, bflo(vraw.y), msgA.z * sc);
            msgA.w = fmaf(p, bfhi(vraw.y), msgA.w * sc);
            msgB.x = fmaf(p, bflo(vraw.z), msgB.x * sc);
            msgB.y = fmaf(p, bfhi(vraw.z), msgB.y * sc);
            msgB.z = fmaf(p, bflo(vraw.w), msgB.z * sc);
            msgB.w = fmaf(p, bfhi(vraw.w), msgB.w * sc);
            sea.x = fmaf(p, ea4.x, sea.x * sc);
            sea.y = fmaf(p, ea4.y, sea.y * sc);
            sea.z = fmaf(p, ea4.z, sea.z * sc);
            sea.w = fmaf(p, ea4.w, sea.w * sc);
            m = mn;
        }
    }

    // merge the 8 groups over g bits (xor 8, 16, 32)
    #pragma unroll
    for (int off = 8; off <= 32; off <<= 1) {
        const float m2 = __shfl_xor(m, off, 64);
        const float l2 = __shfl_xor(l, off, 64);
        float4 a2, b2, s2;
        a2.x = __shfl_xor(msgA.x, off, 64); a2.y = __shfl_xor(msgA.y, off, 64);
        a2.z = __shfl_xor(msgA.z, off, 64); a2.w = __shfl_xor(msgA.w, off, 64);
        b2.x = __shfl_xor(msgB.x, off, 64); b2.y = __shfl_xor(msgB.y, off, 64);
        b2.z = __shfl_xor(msgB.z, off, 64); b2.w = __shfl_xor(msgB.w, off, 64);
        s2.x = __shfl_xor(sea.x, off, 64);  s2.y = __shfl_xor(sea.y, off, 64);
        s2.z = __shfl_xor(sea.z, off, 64);  s2.w = __shfl_xor(sea.w, off, 64);
        const float mn = fmaxf(m, m2);
        const float w1 = __expf(m - mn);
        const float w2 = __expf(m2 - mn);
        l = l * w1 + l2 * w2;
        msgA.x = msgA.x * w1 + a2.x * w2; msgA.y = msgA.y * w1 + a2.y * w2;
        msgA.z = msgA.z * w1 + a2.z * w2; msgA.w = msgA.w * w1 + a2.w * w2;
        msgB.x = msgB.x * w1 + b2.x * w2; msgB.y = msgB.y * w1 + b2.y * w2;
        msgB.z = msgB.z * w1 + b2.z * w2; msgB.w = msgB.w * w1 + b2.w * w2;
        sea.x = sea.x * w1 + s2.x * w2;   sea.y = sea.y * w1 + s2.y * w2;
        sea.z = sea.z * w1 + s2.z * w2;   sea.w = sea.w * w1 + s2.w * w2;
        m = mn;
    }

    // stage merged state in per-wave LDS (any one group; use g==0)
    if (g == 0) {
        *(float4*)&lsea[wave][j * 4]     = sea;
        *(float4*)&lmsg[wave][j * 8]     = msgA;
        *(float4*)&lmsg[wave][j * 8 + 4] = msgB;
    }
    const float inv = (l > 0.f) ? (1.f / l) : 0.f;

    // epilogue: lane handles output channel = lane
    float e = 0.f;
    #pragma unroll 8
    for (int j2 = 0; j2 < DEA; ++j2)
        e = fmaf(lsea[wave][j2], lw[j2 * DIM + lane], e);
    const float msgc = lmsg[wave][lane];
    const float sk = aggskip[(size_t)node * DIM + lane];
    h_out[(size_t)node * DIM + lane] = fmaxf(fmaf(msgc + e, inv, sk), 0.f);
}

// ---------------------------------------------------------------------------
// Final: out = relu(concat(h1,h2) @ skip_w + skip_b), K=128
// ---------------------------------------------------------------------------
__global__ __launch_bounds__(256) void final_kernel(
    const float* __restrict__ h1, const float* __restrict__ h2,
    const float* __restrict__ w, const float* __restrict__ b,
    float* __restrict__ out, int n_nodes)
{
    __shared__ float lw[128 * DIM];   // 32 KB
    __shared__ float lx[16][128];     // 8 KB
    const int tid = threadIdx.x;
    {
        const float4* s4 = (const float4*)w;
        float4* d4 = (float4*)lw;
        #pragma unroll
        for (int i = 0; i < 8; ++i) d4[tid + i * 256] = s4[tid + i * 256];
    }
    const int base = blockIdx.x * 16;
    {
        #pragma unroll
        for (int t = 0; t < 2; ++t) {
            const int f = tid + t * 256;
            const int r = f >> 5;
            const int cf = f & 31;
            const int n = base + r;
            float4 val = make_float4(0.f, 0.f, 0.f, 0.f);
            if (n < n_nodes) {
                if (cf < 16) val = *(const float4*)&h1[(size_t)n * DIM + cf * 4];
                else         val = *(const float4*)&h2[(size_t)n * DIM + (cf - 16) * 4];
            }
            *(float4*)&lx[r][cf * 4] = val;
        }
    }
    __syncthreads();

    const int oc = tid & 63;
    const int nl = tid >> 6;
    float acc[4] = {0, 0, 0, 0};
    #pragma unroll 8
    for (int kk = 0; kk < 128; ++kk) {
        const float wv = lw[kk * DIM + oc];
        #pragma unroll
        for (int r = 0; r < 4; ++r)
            acc[r] = fmaf(lx[nl * 4 + r][kk], wv, acc[r]);
    }
    const float bv = b[oc];
    #pragma unroll
    for (int r = 0; r < 4; ++r) {
        const int n = base + nl * 4 + r;
        if (n < n_nodes) out[(size_t)n * DIM + oc] = fmaxf(acc[r] + bv, 0.f);
    }
}

// ---------------------------------------------------------------------------
extern "C" void kernel_launch(void* const* d_in, const int* in_sizes, int n_in,
                              void* d_out, int out_size, void* d_ws, size_t ws_size,
                              hipStream_t stream)
{
    const float* x     = (const float*)d_in[0];
    const int*   ei    = (const int*)d_in[1];
    const float* eattr = (const float*)d_in[2];
    const float *q1w = (const float*)d_in[3],  *q1b = (const float*)d_in[4];
    const float *k1w = (const float*)d_in[5],  *k1b = (const float*)d_in[6];
    const float *v1w = (const float*)d_in[7],  *v1b = (const float*)d_in[8];
    const float *e1w = (const float*)d_in[9];
    const float *s1w = (const float*)d_in[10], *s1b = (const float*)d_in[11];
    const float *q2w = (const float*)d_in[12], *q2b = (const float*)d_in[13];
    const float *k2w = (const float*)d_in[14], *k2b = (const float*)d_in[15];
    const float *v2w = (const float*)d_in[16], *v2b = (const float*)d_in[17];
    const float *e2w = (const float*)d_in[18];
    const float *s2w = (const float*)d_in[19], *s2b = (const float*)d_in[20];
    const float *skw = (const float*)d_in[21], *skb = (const float*)d_in[22];

    const int N = in_sizes[0] / DIM;
    const int E = in_sizes[1] / 2;
    const int* src = ei;
    const int* dst = ei + E;

    float* ws = (float*)d_ws;
    const size_t nf = (size_t)N * DIM;
    float* q    = ws;                          // nf
    unsigned short* kvb = (unsigned short*)(q + nf);  // N*128 ushorts = nf floats
    float* agg  = q + 2 * nf;                  // nf
    float* h1   = agg + nf;                    // nf
    float* h2   = h1 + nf;                     // nf
    float* qwe  = h2 + nf;                     // 32*N
    int2* pair    = (int2*)(qwe + (size_t)DEA * N);    // E int2
    int* cursor   = (int*)(pair + E);                  // N
    int* row_ptr  = cursor + ((N + 3) & ~3);           // N+1
    const int nb  = (N + 1023) / 1024;
    int* blksum   = row_ptr + ((N + 4) & ~3);          // nb
    int* blkoff   = blksum + ((nb + 3) & ~3);          // nb
    float* wqeW1  = (float*)(blkoff + ((nb + 3) & ~3));// 2048
    float* bqe1   = wqeW1 + 64 * 32;                   // 32
    float* wqeW2  = bqe1 + 32;                         // 2048
    float* bqe2   = wqeW2 + 64 * 32;                   // 32

    const int nblk = (N + 31) / 32;
    const int eblk = (E + 255) / 256;
    const int fblk = (N + 3) / 4;
    const int finblk = (N + 15) / 16;

    // ---------------- CSR over dst + combined score weights ----------------
    hipMemsetAsync(cursor, 0, (size_t)N * sizeof(int), stream);
    hist_kernel<<<eblk, 256, 0, stream>>>(dst, cursor, E, N);
    scan_pass1_kernel<<<nb, 256, 0, stream>>>(cursor, row_ptr, blksum, N);
    scan_pass2_kernel<<<1, 64, 0, stream>>>(blksum, blkoff, row_ptr, nb, N);
    scan_pass3_kernel<<<nb, 256, 0, stream>>>(row_ptr, cursor, blkoff, N);
    scatter_kernel<<<eblk, 256, 0, stream>>>(dst, src, cursor, pair, E, N);
    wqe_prep_kernel<<<2, 256, 0, stream>>>(q1w, q1b, e1w, q2w, q2b, e2w,
                                           wqeW1, bqe1, wqeW2, bqe2);

    // ---------------- layer 1 ----------------
    node_lin_kernel<<<nblk, 256, 0, stream>>>(x, q1w, q1b, k1w, k1b, v1w, v1b,
                                              s1w, s1b, wqeW1, bqe1,
                                              q, kvb, agg, qwe, N);
    fused_edge_kernel<<<fblk, 256, 0, stream>>>(q, qwe, kvb, eattr, e1w, agg,
                                                row_ptr, pair, h1, N);

    // ---------------- layer 2 ----------------
    node_lin_kernel<<<nblk, 256, 0, stream>>>(h1, q2w, q2b, k2w, k2b, v2w, v2b,
                                              s2w, s2b, wqeW2, bqe2,
                                              q, kvb, agg, qwe, N);
    fused_edge_kernel<<<fblk, 256, 0, stream>>>(q, qwe, kvb, eattr, e2w, agg,
                                                row_ptr, pair, h2, N);

    // ---------------- final skip MLP ----------------
    final_kernel<<<finblk, 256, 0, stream>>>(h1, h2, skw, skb, (float*)d_out, N);
}